// Round 10
// baseline (2926.395 us; speedup 1.0000x reference)
//
#include <hip/hip_runtime.h>

#define N_NODES 100000
#define N_EDGES 3200000
#define DIN 128
#define HID 64
#define N_GRAPH 256

#define BSHIFT 7
#define BNODES 128          // nodes per bucket
#define NBK 782             // ceil(N_NODES / 128)
#define CAP 5120            // slots per bucket (avg 4092, sd 64 -> 16 sigma margin)
#define CHUNK 8192          // edges per k_place block
#define EPT (CHUNK / 256)   // edges per thread in k_place

typedef __attribute__((ext_vector_type(8))) short bf16x8;
typedef __attribute__((ext_vector_type(4))) float f32x4;

__device__ inline short bf16_rne(float x) {
  union { float f; unsigned u; } a; a.f = x;
  unsigned r = (a.u + 0x7fffu + ((a.u >> 16) & 1u)) >> 16;
  return (short)r;
}
__device__ inline float bf16_to_f(unsigned short h) {
  union { unsigned u; float f; } b; b.u = ((unsigned)h) << 16;
  return b.f;
}

// ------- pass 1: direct placement into fixed-capacity buckets -------
// packed edge = (src << 7) | (dst & 127); bucket = dst >> 7
__global__ __launch_bounds__(256) void k_place(const int* __restrict__ ei,
                                               int* __restrict__ bcur,
                                               int* __restrict__ pairs) {
  __shared__ int lh[NBK], lbase[NBK], lcur[NBK];
  for (int i = threadIdx.x; i < NBK; i += 256) { lh[i] = 0; lcur[i] = 0; }
  __syncthreads();
  int base = blockIdx.x * CHUNK;
  int srcs[EPT], dsts[EPT];
#pragma unroll
  for (int k = 0; k < EPT; ++k) {
    int e = base + k * 256 + threadIdx.x;
    if (e < N_EDGES) {
      srcs[k] = ei[e];
      dsts[k] = ei[N_EDGES + e];
      atomicAdd(&lh[dsts[k] >> BSHIFT], 1);
    } else {
      dsts[k] = -1;
    }
  }
  __syncthreads();
  for (int i = threadIdx.x; i < NBK; i += 256)
    lbase[i] = lh[i] ? atomicAdd(&bcur[i], lh[i]) : 0;
  __syncthreads();
#pragma unroll
  for (int k = 0; k < EPT; ++k) {
    if (dsts[k] >= 0) {
      int b = dsts[k] >> BSHIFT;
      int l = atomicAdd(&lcur[b], 1);
      pairs[b * CAP + lbase[b] + l] = (srcs[k] << BSHIFT) | (dsts[k] & (BNODES - 1));
    }
  }
}

// ------- pass 2: per-bucket degree histogram -> dinv -------
__global__ __launch_bounds__(256) void k_deg(const int* __restrict__ pairs,
                                             const int* __restrict__ bcur,
                                             float* __restrict__ dinv) {
  __shared__ int lh[BNODES];
  int b = blockIdx.x, t = threadIdx.x;
  if (t < BNODES) lh[t] = 0;
  __syncthreads();
  int cnt = bcur[b];
  const int* pp = pairs + b * CAP;
  for (int j = t; j < cnt; j += 256) atomicAdd(&lh[pp[j] & (BNODES - 1)], 1);
  __syncthreads();
  if (t < BNODES) {
    int n = (b << BSHIFT) + t;
    if (n < N_NODES) dinv[n] = rsqrtf((float)(lh[t] + 1));  // +1 self loop
  }
}

// -------- MFMA GEMM (split-bf16 f32 emulation): Hs = bf16((X @ W) * dinv[row]) --------
// P-layout epilogue: uint j of row holds (bf16 feat j, bf16 feat j+32)
template <int K>
__global__ __launch_bounds__(256) void k_gemm_mfma(const float* __restrict__ X,
                                                   const float* __restrict__ W,
                                                   const float* __restrict__ dinv,
                                                   unsigned* __restrict__ Hs32) {
  __shared__ short WTh[64 * K];  // W^T hi, [n][k] bf16, XOR-swizzled
  __shared__ short WTl[64 * K];  // W^T lo
  const int t = threadIdx.x;
  constexpr int KC = K / 8;
  if (t < 16 * KC) {
    int ng = t / KC;            // n-group of 4
    int k0 = (t % KC) * 8;
    float w[8][4];
#pragma unroll
    for (int j = 0; j < 8; ++j)
      *(f32x4*)&w[j][0] = *(const f32x4*)&W[(k0 + j) * HID + ng * 4];
#pragma unroll
    for (int c = 0; c < 4; ++c) {
      int n = ng * 4 + c;
      union { short s[8]; int4 i4; } uh, ul;
#pragma unroll
      for (int j = 0; j < 8; ++j) {
        short hi = bf16_rne(w[j][c]);
        uh.s[j] = hi;
        ul.s[j] = bf16_rne(w[j][c] - bf16_to_f((unsigned short)hi));
      }
      int byte = (n * K + k0) * 2;
      byte ^= ((n & 7) << 4);
      *(int4*)((char*)WTh + byte) = uh.i4;
      *(int4*)((char*)WTl + byte) = ul.i4;
    }
  }
  __syncthreads();
  const int wave = t >> 6, lane = t & 63;
  const int row0 = blockIdx.x * 64 + wave * 16;
  if (row0 >= N_NODES) return;
  const int mrow = lane & 15;  // A-row within tile / D-col within tile
  const int kq = lane >> 4;    // k-quarter
  f32x4 acc[4] = {f32x4{0,0,0,0}, f32x4{0,0,0,0}, f32x4{0,0,0,0}, f32x4{0,0,0,0}};
#pragma unroll
  for (int kk = 0; kk < K; kk += 32) {
    int k0 = kk + kq * 8;
    const float* xp = &X[(long)(row0 + mrow) * K + k0];
    f32x4 v0 = *(const f32x4*)xp;
    f32x4 v1 = *(const f32x4*)(xp + 4);
    union { short s[8]; bf16x8 v; } ah, al;
#pragma unroll
    for (int j = 0; j < 4; ++j) {
      short h0 = bf16_rne(v0[j]);
      ah.s[j] = h0;
      al.s[j] = bf16_rne(v0[j] - bf16_to_f((unsigned short)h0));
      short h1 = bf16_rne(v1[j]);
      ah.s[4 + j] = h1;
      al.s[4 + j] = bf16_rne(v1[j] - bf16_to_f((unsigned short)h1));
    }
#pragma unroll
    for (int nt = 0; nt < 4; ++nt) {
      int n = nt * 16 + mrow;
      int byte = (n * K + k0) * 2;
      byte ^= ((n & 7) << 4);
      bf16x8 bh = *(bf16x8*)((char*)WTh + byte);
      bf16x8 bl = *(bf16x8*)((char*)WTl + byte);
      acc[nt] = __builtin_amdgcn_mfma_f32_16x16x32_bf16(ah.v, bh, acc[nt], 0, 0, 0);
      acc[nt] = __builtin_amdgcn_mfma_f32_16x16x32_bf16(ah.v, bl, acc[nt], 0, 0, 0);
      acc[nt] = __builtin_amdgcn_mfma_f32_16x16x32_bf16(al.v, bh, acc[nt], 0, 0, 0);
    }
  }
  // D: col(feat) = nt*16 + mrow, row = kq*4 + r  [measured m89 layout]
  // feats of this thread: mrow(nt0), 16+mrow(nt1), 32+mrow(nt2), 48+mrow(nt3)
  // P-layout: uint mrow = (feat mrow, feat mrow+32); uint 16+mrow = (16+mrow, 48+mrow)
#pragma unroll
  for (int r = 0; r < 4; ++r) {
    int row = row0 + kq * 4 + r;
    float dv = dinv[row];
    unsigned lo0 = (unsigned short)bf16_rne(acc[0][r] * dv);
    unsigned hi0 = (unsigned short)bf16_rne(acc[2][r] * dv);
    unsigned lo1 = (unsigned short)bf16_rne(acc[1][r] * dv);
    unsigned hi1 = (unsigned short)bf16_rne(acc[3][r] * dv);
    Hs32[((long)row << 5) + mrow]      = lo0 | (hi0 << 16);
    Hs32[((long)row << 5) + 16 + mrow] = lo1 | (hi1 << 16);
  }
}

// ------- gather: one block per 128-node bucket, LDS f32 accumulators -------
// out[n] = act(dinv[n]*(hs[n] + sum_{src->n} hs[src]) + bias)
template <bool RELU>
__global__ __launch_bounds__(256) void k_gather(const unsigned* __restrict__ hs32,
                                                const int* __restrict__ pairs,
                                                const int* __restrict__ bcur,
                                                const float* __restrict__ dinv,
                                                const float* __restrict__ bias,
                                                float* __restrict__ ob) {
  __shared__ float lacc[BNODES * 64];  // 32 KB
  int t = threadIdx.x, b = blockIdx.x;
  for (int i = t; i < BNODES * 64; i += 256) lacc[i] = 0.f;
  __syncthreads();
  int cnt = bcur[b];
  const int* pp = pairs + b * CAP;
  int lane = t & 63, wave = t >> 6, half = lane >> 5, hl = lane & 31;
  const int SENT = (N_NODES << BSHIFT);  // src=sentinel zero row, dlo=0 (+0.0, harmless)
  for (int j0 = wave * 64; j0 < cnt; j0 += 256) {
    int rem = cnt - j0;
    int myp = (lane < rem) ? pp[j0 + lane] : SENT;
    int ngrp = (min(64, rem) + 7) >> 3;  // groups of 8 edges, 2 per wave-step
    for (int g = 0; g < ngrp; ++g) {
      int base8 = 8 * g + half;
      int p0 = __shfl(myp, base8 + 0);
      int p1 = __shfl(myp, base8 + 2);
      int p2 = __shfl(myp, base8 + 4);
      int p3 = __shfl(myp, base8 + 6);
      unsigned u0 = hs32[((unsigned)(p0 >> BSHIFT) << 5) + hl];
      unsigned u1 = hs32[((unsigned)(p1 >> BSHIFT) << 5) + hl];
      unsigned u2 = hs32[((unsigned)(p2 >> BSHIFT) << 5) + hl];
      unsigned u3 = hs32[((unsigned)(p3 >> BSHIFT) << 5) + hl];
      union { unsigned u; float f; } lo, hi;
      int d;
      d = (p0 & (BNODES - 1)) << 6;
      lo.u = u0 << 16;          atomicAdd(&lacc[d + hl], lo.f);
      hi.u = u0 & 0xffff0000u;  atomicAdd(&lacc[d + 32 + hl], hi.f);
      d = (p1 & (BNODES - 1)) << 6;
      lo.u = u1 << 16;          atomicAdd(&lacc[d + hl], lo.f);
      hi.u = u1 & 0xffff0000u;  atomicAdd(&lacc[d + 32 + hl], hi.f);
      d = (p2 & (BNODES - 1)) << 6;
      lo.u = u2 << 16;          atomicAdd(&lacc[d + hl], lo.f);
      hi.u = u2 & 0xffff0000u;  atomicAdd(&lacc[d + 32 + hl], hi.f);
      d = (p3 & (BNODES - 1)) << 6;
      lo.u = u3 << 16;          atomicAdd(&lacc[d + hl], lo.f);
      hi.u = u3 & 0xffff0000u;  atomicAdd(&lacc[d + 32 + hl], hi.f);
    }
  }
  __syncthreads();
  int n0 = b << BSHIFT;
  for (int i = t; i < BNODES * 64; i += 256) {
    int n = n0 + (i >> 6);
    if (n >= N_NODES) break;  // i (and node) strictly increasing per thread
    int f = i & 63;
    unsigned us = hs32[((unsigned)n << 5) + (f & 31)];
    union { unsigned u; float f_; } sv;
    sv.u = (f < 32) ? (us << 16) : (us & 0xffff0000u);
    float v = dinv[n] * (lacc[i] + sv.f_) + bias[f];
    if (RELU) v = fmaxf(v, 0.f);
    ob[((long)n << 6) + f] = v;
  }
}

// ---------------- fused pooling (mean+max) + MLP head ----------------
__global__ __launch_bounds__(256) void k_poolhead(const float* __restrict__ Hf,
                                                  const int* __restrict__ batch,
                                                  const float* __restrict__ fcW1,
                                                  const float* __restrict__ fcb1,
                                                  const float* __restrict__ fcW2,
                                                  const float* __restrict__ fcb2,
                                                  float* __restrict__ out) {
  int g = blockIdx.x;
  int start, end;
  {
    int lo = 0, hi = N_NODES;
    while (lo < hi) { int mid = (lo + hi) >> 1; if (batch[mid] < g) lo = mid + 1; else hi = mid; }
    start = lo;
    lo = start; hi = N_NODES;
    while (lo < hi) { int mid = (lo + hi) >> 1; if (batch[mid] < g + 1) lo = mid + 1; else hi = mid; }
    end = lo;
  }
  int lane = threadIdx.x & 63, wave = threadIdx.x >> 6;
  float sum = 0.f, mx = -INFINITY;
  for (int n = start + wave; n < end; n += 4) {
    float v = Hf[((long)n << 6) + lane];
    sum += v;
    mx = fmaxf(mx, v);
  }
  __shared__ float ssum[4][HID];
  __shared__ float smax[4][HID];
  __shared__ float p[2 * HID];
  ssum[wave][lane] = sum;
  smax[wave][lane] = mx;
  __syncthreads();
  if (wave == 0) {
    sum = ssum[0][lane] + ssum[1][lane] + ssum[2][lane] + ssum[3][lane];
    mx = fmaxf(fmaxf(smax[0][lane], smax[1][lane]), fmaxf(smax[2][lane], smax[3][lane]));
    int cnt = end - start;
    float mean;
    if (cnt == 0) { mean = 0.f; mx = 0.f; }
    else mean = sum / (float)cnt;
    p[lane] = mean;
    p[HID + lane] = mx;
    // MLP head (wave 0 only)
    float acc = fcb1[lane];
#pragma unroll
    for (int k = 0; k < 2 * HID; ++k) acc += p[k] * fcW1[k * HID + lane];
    acc = fmaxf(acc, 0.f);
    float contrib = acc * fcW2[lane];
#pragma unroll
    for (int off = 32; off > 0; off >>= 1) contrib += __shfl_down(contrib, off);
    if (lane == 0) out[g] = contrib + fcb2[0];
  }
}

extern "C" void kernel_launch(void* const* d_in, const int* in_sizes, int n_in,
                              void* d_out, int out_size, void* d_ws, size_t ws_size,
                              hipStream_t stream) {
  const float* x    = (const float*)d_in[0];
  const int*   ei   = (const int*)d_in[1];
  const int*   bat  = (const int*)d_in[2];
  const float* W1   = (const float*)d_in[3];
  const float* b1   = (const float*)d_in[4];
  const float* W2   = (const float*)d_in[5];
  const float* b2   = (const float*)d_in[6];
  const float* fcW1 = (const float*)d_in[7];
  const float* fcb1 = (const float*)d_in[8];
  const float* fcW2 = (const float*)d_in[9];
  const float* fcb2 = (const float*)d_in[10];
  float* out = (float*)d_out;

  char* ws = (char*)d_ws;
  size_t off = 0;
  auto align = [&]() { off = (off + 127) & ~127ul; };
  int*   bcur  = (int*)(ws + off);   off += NBK * 4;                align();
  float* dinv  = (float*)(ws + off); off += N_NODES * 4;            align();
  int*   pairs = (int*)(ws + off);   off += (size_t)NBK * CAP * 4;  align();
  unsigned short* hs = (unsigned short*)(ws + off);
  off += ((size_t)N_NODES + 1) * HID * 2;  // +1 zero sentinel row
  align();
  float* ob = (float*)(ws + off);    off += (size_t)N_NODES * HID * 4;
  unsigned* hs32 = (unsigned*)hs;

  // init: bucket cursors + sentinel row (ws is poisoned 0xAA before every call)
  hipMemsetAsync(bcur, 0, NBK * sizeof(int), stream);
  hipMemsetAsync(hs + (size_t)N_NODES * HID, 0, HID * 2, stream);

  // ---- bucketed edge placement (unsorted within bucket) + degree/dinv ----
  k_place<<<(N_EDGES + CHUNK - 1) / CHUNK, 256, 0, stream>>>(ei, bcur, pairs);
  k_deg<<<NBK, 256, 0, stream>>>(pairs, bcur, dinv);

  // ---- layer 1: hs1 = bf16((x@W1)*dinv) ; ob = relu(dinv*(hs1 + gather) + b1) ----
  k_gemm_mfma<DIN><<<(N_NODES + 63) / 64, 256, 0, stream>>>(x, W1, dinv, hs32);
  k_gather<true><<<NBK, 256, 0, stream>>>(hs32, pairs, bcur, dinv, b1, ob);

  // ---- layer 2: hs2 = bf16((ob@W2)*dinv) ; ob = dinv*(hs2 + gather) + b2 ----
  k_gemm_mfma<HID><<<(N_NODES + 63) / 64, 256, 0, stream>>>(ob, W2, dinv, hs32);
  k_gather<false><<<NBK, 256, 0, stream>>>(hs32, pairs, bcur, dinv, b2, ob);

  // ---- fused pooling + head ----
  k_poolhead<<<N_GRAPH, 256, 0, stream>>>(ob, bat, fcW1, fcb1, fcW2, fcb2, out);
}